// Round 5
// baseline (1301.558 us; speedup 1.0000x reference)
//
#include <hip/hip_runtime.h>
#include <hip/hip_bf16.h>
#include <stdint.h>

#define VOCAB 32000
#define HID   256
#define BATCH 16
#define SEQT  256
#define ROWS  (BATCH*SEQT)   // 4096

#define NWORKERS 255
#define NTILES   (32*125)    // 32 m-panels x 125 n-panels(256 wide)

typedef __attribute__((ext_vector_type(8))) short bf16x8_t;
typedef __attribute__((ext_vector_type(4))) float f32x4_t;

__device__ __forceinline__ short f2bs(float x) {
    __hip_bfloat16 h = __float2bfloat16(x);
    return *reinterpret_cast<short*>(&h);
}
__device__ __forceinline__ bf16x8_t cvt8(float4 a, float4 b) {
    union { short s[8]; bf16x8_t v; } u;
    u.s[0] = f2bs(a.x); u.s[1] = f2bs(a.y); u.s[2] = f2bs(a.z); u.s[3] = f2bs(a.w);
    u.s[4] = f2bs(b.x); u.s[5] = f2bs(b.y); u.s[6] = f2bs(b.z); u.s[7] = f2bs(b.w);
    return u.v;
}
// workgroup barrier draining ONLY lgkmcnt; vmem stays in flight
__device__ __forceinline__ void barrier_lds() {
    asm volatile("s_waitcnt lgkmcnt(0)\n\ts_barrier" ::: "memory");
}
// tanh via exp2: tanh(x) = 1 - 2/(2^(2*log2(e)*x)+1); saturates naturally.
__device__ __forceinline__ float tanh_exp(float x) {
    float e = __builtin_amdgcn_exp2f(x * 2.885390081777927f);
    return fmaf(-2.f, __builtin_amdgcn_rcpf(e + 1.f), 1.f);
}
// pack two f32 -> one dword of 2 bf16 (RNE), lo = first operand
__device__ __forceinline__ uint32_t pk_bf16(float lo, float hi) {
    uint32_t r;
    asm("v_cvt_pk_bf16_f32 %0, %1, %2" : "=v"(r) : "v"(lo), "v"(hi));
    return r;
}
// async global->LDS, 16B per lane: LDS dest = wave-uniform base + lane*16,
// global src = per-lane pointer. Counts against vmcnt.
__device__ __forceinline__ void gload_lds16(const short* g, short* lds_base) {
    __builtin_amdgcn_global_load_lds(
        (const __attribute__((address_space(1))) void*)g,
        (__attribute__((address_space(3))) void*)lds_base, 16, 0, 0);
}

// ===========================================================================
// Swizzled fragment layout (shared by A=hs and B=Wfcb):
//   element (row, k) -> swz[ (row>>4)*4096 + (k>>5)*512 + ((k>>3)&3)*128
//                            + (row&15)*8 + (k&7) ]
// A fragment (one 16-row tile, one ki) is 1 KB contiguous, lane-linear ->
// stageable with ONE global_load_lds wave-instruction.
// ===========================================================================

// ---------------------------------------------------------------------------
// K1: xp = Wih[inputs]+bih+bhh; zeroes S; inits progress flag; converts
// Wfc fp32 -> bf16 into SWIZZLED Wfcb (coalesced-write direction).
// ---------------------------------------------------------------------------
__global__ __launch_bounds__(256) void xproj_kernel(
    const int* __restrict__ inputs,
    const float* __restrict__ Wih,
    const float* __restrict__ bih,
    const float* __restrict__ bhh,
    const float* __restrict__ Wfc,
    float* __restrict__ xp,
    float* __restrict__ S,
    __hip_bfloat16* __restrict__ Wfcb,
    int* __restrict__ prog,
    int do_cvt)
{
    int idx = blockIdx.x * 256 + threadIdx.x;  // (t*16+b)*256 + h
    int h  = idx & 255;
    int tb = idx >> 8;
    int b  = tb & 15;
    int t  = tb >> 4;
    int id = inputs[b * SEQT + t];
    xp[idx] = Wih[(size_t)id * HID + h] + bih[h] + bhh[h];
    if (idx < ROWS) S[idx] = 0.0f;
    if (do_cvt) {
        if (idx == 0) prog[0] = -1;             // reset producer progress
        if (idx < (VOCAB * HID / 8)) {
            int e   = idx * 8;
            int m   = (e >> 3) & 15;
            int lhh = (e >> 7) & 3;
            int ki  = (e >> 9) & 7;
            int tile = e >> 12;
            const float4* p = (const float4*)(Wfc + (size_t)(tile * 16 + m) * HID
                                              + ki * 32 + lhh * 8);
            *(bf16x8_t*)((short*)Wfcb + (size_t)e) = cvt8(p[0], p[1]);
        }
    }
}

// ---------------------------------------------------------------------------
// RNN producer core: 512 threads (8 waves, REVERTED from the 4-wave R4
// regression - step is latency-bound, 2 waves/SIMD needed). Lane owns cols
// (n0, n0+1); x folded into MFMA C-in; h stored direct-from-register to the
// swizzled global layout with AGENT-scope (sc1 write-through) stores so
// consumer XCDs never see stale data. Publishes prog = t-1 every 8 steps
// after a counted vmcnt(8) drain (step t issues exactly 8 vmem ops, so
// vmcnt(8) retires all of step t-1's stores; in-order vmcnt retirement).
// ---------------------------------------------------------------------------
__device__ void rnn_core(const float* __restrict__ xp,
                         const float* __restrict__ Whh,
                         __hip_bfloat16* __restrict__ hs,
                         int* __restrict__ prog)
{
    __shared__ __align__(8) short hbuf[2][16][264];   // +8 pad
    const int tid = threadIdx.x;
    const int l = tid & 63, w = tid >> 6;
    const int lr = l & 15, lh = l >> 4;
    const int n0 = w * 32 + lr * 2;
    // swizzled global base for this lane's column pair
    short* hsg = (short*)hs + (n0 >> 5) * 512 + (((n0 >> 3) & 3) * 128) + (n0 & 7);

    bf16x8_t bfrag[2][8];
#pragma unroll
    for (int nt = 0; nt < 2; nt++)
#pragma unroll
        for (int ki = 0; ki < 8; ki++) {
            const float4* p = (const float4*)(Whh + (size_t)(n0 + nt) * HID + ki * 32 + lh * 8);
            bfrag[nt][ki] = cvt8(p[0], p[1]);
        }
    for (int i = tid; i < 16 * 264; i += 512) ((short*)hbuf[0])[i] = 0;
    __syncthreads();

    float2 xva[4], xvb[4];
#pragma unroll
    for (int r = 0; r < 4; r++)
        xva[r] = *(const float2*)(xp + (lh * 4 + r) * HID + n0);

    auto step = [&](int SRC, int DST, float2* xc, float2* xn, int t) {
        bf16x8_t afr[8];
#pragma unroll
        for (int ki = 0; ki < 8; ki++)
            afr[ki] = *(const bf16x8_t*)(&hbuf[SRC][lr][ki * 32 + lh * 8]);

        f32x4_t a0a = {xc[0].x, xc[1].x, xc[2].x, xc[3].x};
        f32x4_t a1a = {xc[0].y, xc[1].y, xc[2].y, xc[3].y};
        f32x4_t a0b = {0.f, 0.f, 0.f, 0.f};
        f32x4_t a1b = {0.f, 0.f, 0.f, 0.f};
#pragma unroll
        for (int ki = 0; ki < 4; ki++) {
            a0a = __builtin_amdgcn_mfma_f32_16x16x32_bf16(afr[ki],     bfrag[0][ki],     a0a, 0, 0, 0);
            a0b = __builtin_amdgcn_mfma_f32_16x16x32_bf16(afr[ki + 4], bfrag[0][ki + 4], a0b, 0, 0, 0);
            a1a = __builtin_amdgcn_mfma_f32_16x16x32_bf16(afr[ki],     bfrag[1][ki],     a1a, 0, 0, 0);
            a1b = __builtin_amdgcn_mfma_f32_16x16x32_bf16(afr[ki + 4], bfrag[1][ki + 4], a1b, 0, 0, 0);
        }

        if (t + 1 < SEQT) {
            const float* xb = xp + (size_t)(t + 1) * (BATCH * HID);
#pragma unroll
            for (int r = 0; r < 4; r++)
                xn[r] = *(const float2*)(xb + (lh * 4 + r) * HID + n0);
        }

#pragma unroll
        for (int r = 0; r < 4; r++) {
            float v0 = a0a[r] + a0b[r];
            float v1 = a1a[r] + a1b[r];
            uint32_t pk = pk_bf16(tanh_exp(v0), tanh_exp(v1));
            *(uint32_t*)(&hbuf[DST][lh * 4 + r][n0]) = pk;
            // write-through (agent scope -> sc1): visible to all XCD L2s
            __hip_atomic_store((uint32_t*)(hsg + (size_t)t * 4096 + (lh * 4 + r) * 8),
                               pk, __ATOMIC_RELAXED, __HIP_MEMORY_SCOPE_AGENT);
        }
        const bool pub = (prog != nullptr) && t && ((t & 7) == 0);
        if (pub) asm volatile("s_waitcnt vmcnt(8)" ::: "memory");
        barrier_lds();
        if (pub && tid == 0)
            __hip_atomic_store(prog, t - 1, __ATOMIC_RELAXED, __HIP_MEMORY_SCOPE_AGENT);
    };

    for (int t = 0; t < SEQT; t += 2) {
        step(0, 1, xva, xvb, t);
        step(1, 0, xvb, xva, t + 1);
    }
    if (prog != nullptr) {
        asm volatile("s_waitcnt vmcnt(0)" ::: "memory");
        __syncthreads();
        if (tid == 0)
            __hip_atomic_store(prog, SEQT - 1, __ATOMIC_RELAXED, __HIP_MEMORY_SCOPE_AGENT);
    }
}

// ---------------------------------------------------------------------------
// FC worker core: persistent block, grid-strides m-ordered over 128x256
// tiles; polls prog >= m_id*8+7, agent-acquire fence (buffer_inv) on grant.
// Per tile: R4-proven global_load_lds + counted-vmcnt(3) 2-slab pipeline,
// 8 waves: wave w stages A row-tile w + B col-tiles {2w,2w+1}; computes
// 64x64 (wm=(w>>2)*64, wn=(w&3)*64). Fused bias+exp+rowsum+target epilogue.
// ---------------------------------------------------------------------------
__device__ void fc_worker(
    const __hip_bfloat16* __restrict__ hsz,
    const __hip_bfloat16* __restrict__ Wfcb,
    const float* __restrict__ bfc,
    const int* __restrict__ targets,
    float* __restrict__ S,
    float* __restrict__ TL,
    int* __restrict__ prog,
    int wid)
{
    __shared__ __align__(16) short As[2][8][512];
    __shared__ __align__(16) short Bs[2][16][512];
    __shared__ int tgt[128];

    const int tid = threadIdx.x;
    const int l = tid & 63, w = tid >> 6;
    const int lr = l & 15, lh = l >> 4;
    const int wm = (w >> 2) * 64, wn = (w & 3) * 64;

    for (int ti = wid; ti < NTILES; ti += NWORKERS) {
        const int m_id = ti / 125;
        const int n2   = ti - m_id * 125;
        const int m0 = m_id * 128, n0 = n2 * 256;

        if (tid == 0) {
            const int need = m_id * 8 + 7;
            int spin = 0;
            while (__hip_atomic_load(prog, __ATOMIC_RELAXED, __HIP_MEMORY_SCOPE_AGENT) < need) {
                __builtin_amdgcn_s_sleep(4);
                if (++spin > (1 << 18)) break;   // safety bound; never hit if sync works
            }
            __builtin_amdgcn_fence(__ATOMIC_ACQUIRE, "agent");   // buffer_inv: drop stale L2
        }
        __syncthreads();

        if (tid < 128) {
            int r = m0 + tid;                    // r = t*16+b
            tgt[tid] = targets[((r & 15) << 8) | (r >> 4)];
        }
        __builtin_amdgcn_sched_barrier(0);

        const short* Ag = (const short*)hsz  + (size_t)(m_id * 8 + w)  * 4096 + l * 8;
        const short* Bg = (const short*)Wfcb + (size_t)(n2 * 16 + 2*w) * 4096 + l * 8;

        f32x4_t acc[4][4];
        const f32x4_t z = {0.f, 0.f, 0.f, 0.f};
#pragma unroll
        for (int i = 0; i < 4; i++)
#pragma unroll
            for (int jj = 0; jj < 4; jj++) acc[i][jj] = z;

        auto stage = [&](int buf, int s) {     // 3 wave-instrs, zero VALU
            gload_lds16(Ag + s * 512,        &As[buf][w][0]);
            gload_lds16(Bg + s * 512,        &Bs[buf][2 * w][0]);
            gload_lds16(Bg + 4096 + s * 512, &Bs[buf][2 * w + 1][0]);
        };
        stage(0, 0);
        stage(1, 1);
        __builtin_amdgcn_sched_barrier(0);

#pragma unroll
        for (int s = 0; s < 8; s++) {
            const int buf = s & 1;
            // own stage(s) landed (FIFO, 3 newer ops may remain) -> barrier
            if (s < 7) asm volatile("s_waitcnt vmcnt(3)\n\ts_barrier" ::: "memory");
            else       asm volatile("s_waitcnt vmcnt(0)\n\ts_barrier" ::: "memory");

            bf16x8_t a[4], b[4];
#pragma unroll
            for (int mt = 0; mt < 4; mt++)
                a[mt] = *(const bf16x8_t*)&As[buf][(w >> 2) * 4 + mt][l * 8];
#pragma unroll
            for (int nt = 0; nt < 4; nt++)
                b[nt] = *(const bf16x8_t*)&Bs[buf][(w & 3) * 4 + nt][l * 8];

            if (s < 6) {
                barrier_lds();                // all waves done reading buf
                stage(buf, s + 2);            // refill 2 slabs ahead
                __builtin_amdgcn_sched_barrier(0);
            }
#pragma unroll
            for (int mt = 0; mt < 4; mt++)
#pragma unroll
                for (int nt = 0; nt < 4; nt++)
                    acc[mt][nt] = __builtin_amdgcn_mfma_f32_16x16x32_bf16(
                        a[mt], b[nt], acc[mt][nt], 0, 0, 0);
        }

        // epilogue: bias + exp + rowsum; extract target logits inline
        int tg[16];
#pragma unroll
        for (int i = 0; i < 16; i++)
            tg[i] = tgt[wm + (i >> 2) * 16 + lh * 4 + (i & 3)];

        float rsum[16];
#pragma unroll
        for (int i = 0; i < 16; i++) rsum[i] = 0.f;
#pragma unroll
        for (int nt = 0; nt < 4; nt++) {
            int n = n0 + wn + nt * 16 + lr;
            float bias = bfc[n];
#pragma unroll
            for (int mt = 0; mt < 4; mt++)
#pragma unroll
                for (int r = 0; r < 4; r++) {
                    float v = acc[mt][nt][r] + bias;
                    rsum[mt * 4 + r] += __expf(v);
                    if (tg[mt * 4 + r] == n)
                        TL[m0 + wm + mt * 16 + lh * 4 + r] = v;
                }
        }
#pragma unroll
        for (int m = 1; m < 16; m <<= 1)
#pragma unroll
            for (int i = 0; i < 16; i++) rsum[i] += __shfl_xor(rsum[i], m, 64);
        if (lr == 0) {
#pragma unroll
            for (int i = 0; i < 16; i++) {
                int r = m0 + wm + (i >> 2) * 16 + lh * 4 + (i & 3);
                atomicAdd(&S[r], rsum[i]);
            }
        }
    }
}

// ---------------------------------------------------------------------------
// Fused cooperative kernel: block 0 = RNN producer, blocks 1..255 = FC
// workers hiding the FC GEMM under the recurrence. 256 blocks x 512 thr,
// ~65 KB LDS -> 1 block/CU co-residency guaranteed.
// ---------------------------------------------------------------------------
__global__ __launch_bounds__(512, 1) void rnnfc_kernel(
    const float* __restrict__ xp,
    const float* __restrict__ Whh,
    __hip_bfloat16* __restrict__ hs,
    const __hip_bfloat16* __restrict__ Wfcb,
    const float* __restrict__ bfc,
    const int* __restrict__ targets,
    float* __restrict__ S,
    float* __restrict__ TL,
    int* __restrict__ prog)
{
    if (blockIdx.x == 0) rnn_core(xp, Whh, hs, prog);
    else                 fc_worker(hs, Wfcb, bfc, targets, S, TL, prog, (int)blockIdx.x - 1);
}

// standalone fallback producer (no publishing)
__global__ __launch_bounds__(512, 1) void rnn_kernel(
    const float* __restrict__ xp,
    const float* __restrict__ Whh,
    __hip_bfloat16* __restrict__ hs)
{
    rnn_core(xp, Whh, hs, nullptr);
}

// ---------------------------------------------------------------------------
// Standalone FC (fallback path only): R4 structure, 256 threads, 8192 blocks.
// ---------------------------------------------------------------------------
template <bool BF16B>
__global__ __launch_bounds__(256) void fc_kernel(
    const __hip_bfloat16* __restrict__ hsz,
    const void* __restrict__ WfcP,
    const float* __restrict__ bfc,
    const int* __restrict__ targets,
    float* __restrict__ S,
    float* __restrict__ TL)
{
    __shared__ __align__(16) short As[2][8 * 512];
    __shared__ __align__(16) short Bs[2][8 * 512];
    __shared__ int tgt[128];

    const int bid = blockIdx.x;
    const int xcd = bid & 7;
    const int j   = bid >> 3;
    const int m_id = j & 31;
    const int n_id = (j >> 5) * 8 + xcd;
    if (n_id >= VOCAB / 128) return;
    const int m0 = m_id * 128, n0 = n_id * 128;

    const int tid = threadIdx.x;
    const int l = tid & 63, w = tid >> 6;
    const int lr = l & 15, lh = l >> 4;
    const int wm = (w >> 1) * 64, wn = (w & 1) * 64;

    if (tid < 128) {
        int r = m0 + tid;
        tgt[tid] = targets[((r & 15) << 8) | (r >> 4)];
    }
    __builtin_amdgcn_sched_barrier(0);

    const short* Ag = (const short*)hsz + (size_t)m_id * 32768 + (size_t)(w * 2) * 4096 + l * 8;
    const short* Bg = (const short*)WfcP + (size_t)n_id * 32768 + (size_t)(w * 2) * 4096 + l * 8;
    const float* Bf = (const float*)WfcP;

    f32x4_t acc[4][4];
    const f32x4_t z = {0.f, 0.f, 0.f, 0.f};
#pragma unroll
    for (int i = 0; i < 4; i++)
#pragma unroll
        for (int jj = 0; jj < 4; jj++) acc[i][jj] = z;

    if (BF16B) {
        auto stage = [&](int buf, int s) {
            gload_lds16(Ag + s * 512,        &As[buf][(w * 2) * 512]);
            gload_lds16(Ag + 4096 + s * 512, &As[buf][(w * 2 + 1) * 512]);
            gload_lds16(Bg + s * 512,        &Bs[buf][(w * 2) * 512]);
            gload_lds16(Bg + 4096 + s * 512, &Bs[buf][(w * 2 + 1) * 512]);
        };
        stage(0, 0);
        stage(1, 1);
        __builtin_amdgcn_sched_barrier(0);

#pragma unroll
        for (int s = 0; s < 8; s++) {
            const int buf = s & 1;
            if (s < 7) asm volatile("s_waitcnt vmcnt(4)\n\ts_barrier" ::: "memory");
            else       asm volatile("s_waitcnt vmcnt(0)\n\ts_barrier" ::: "memory");

            bf16x8_t a[4], b[4];
#pragma unroll
            for (int mt = 0; mt < 4; mt++)
                a[mt] = *(const bf16x8_t*)&As[buf][(((w >> 1) * 4 + mt) * 512) + l * 8];
#pragma unroll
            for (int nt = 0; nt < 4; nt++)
                b[nt] = *(const bf16x8_t*)&Bs[buf][(((w & 1) * 4 + nt) * 512) + l * 8];

            if (s < 6) {
                barrier_lds();
                stage(buf, s + 2);
                __builtin_amdgcn_sched_barrier(0);
            }
#pragma unroll
            for (int mt = 0; mt < 4; mt++)
#pragma unroll
                for (int nt = 0; nt < 4; nt++)
                    acc[mt][nt] = __builtin_amdgcn_mfma_f32_16x16x32_bf16(
                        a[mt], b[nt], acc[mt][nt], 0, 0, 0);
        }
    } else {
        for (int s = 0; s < 8; s++) {
            __syncthreads();
#pragma unroll
            for (int i = 0; i < 2; i++) {
                int tt = w * 2 + i;
                bf16x8_t va = *(const bf16x8_t*)(Ag + i * 4096 + s * 512);
                *(bf16x8_t*)&As[0][tt * 512 + l * 8] = va;
                int n = n0 + tt * 16 + lr;
                const float4* p = (const float4*)(Bf + (size_t)n * HID + s * 32 + lh * 8);
                *(bf16x8_t*)&Bs[0][tt * 512 + l * 8] = cvt8(p[0], p[1]);
            }
            __syncthreads();
            bf16x8_t a[4], b[4];
#pragma unroll
            for (int mt = 0; mt < 4; mt++)
                a[mt] = *(const bf16x8_t*)&As[0][(((w >> 1) * 4 + mt) * 512) + l * 8];
#pragma unroll
            for (int nt = 0; nt < 4; nt++)
                b[nt] = *(const bf16x8_t*)&Bs[0][(((w & 1) * 4 + nt) * 512) + l * 8];
#pragma unroll
            for (int mt = 0; mt < 4; mt++)
#pragma unroll
                for (int nt = 0; nt < 4; nt++)
                    acc[mt][nt] = __builtin_amdgcn_mfma_f32_16x16x32_bf16(
                        a[mt], b[nt], acc[mt][nt], 0, 0, 0);
        }
    }

    int tg[16];
#pragma unroll
    for (int i = 0; i < 16; i++)
        tg[i] = tgt[wm + (i >> 2) * 16 + lh * 4 + (i & 3)];

    float rsum[16];
#pragma unroll
    for (int i = 0; i < 16; i++) rsum[i] = 0.f;
#pragma unroll
    for (int nt = 0; nt < 4; nt++) {
        int n = n0 + wn + nt * 16 + lr;
        float bias = bfc[n];
#pragma unroll
        for (int mt = 0; mt < 4; mt++)
#pragma unroll
            for (int r = 0; r < 4; r++) {
                float v = acc[mt][nt][r] + bias;
                rsum[mt * 4 + r] += __expf(v);
                if (tg[mt * 4 + r] == n)
                    TL[m0 + wm + mt * 16 + lh * 4 + r] = v;
            }
    }
#pragma unroll
    for (int m = 1; m < 16; m <<= 1)
#pragma unroll
        for (int i = 0; i < 16; i++) rsum[i] += __shfl_xor(rsum[i], m, 64);
    if (lr == 0) {
#pragma unroll
        for (int i = 0; i < 16; i++) {
            int r = m0 + wm + (i >> 2) * 16 + lh * 4 + (i & 3);
            atomicAdd(&S[r], rsum[i]);
        }
    }
}

// ---------------------------------------------------------------------------
// K4: loss = mean_r( log(S[r]) - TL[r] )
// ---------------------------------------------------------------------------
__global__ __launch_bounds__(256) void loss_kernel(
    const float* __restrict__ S,
    const float* __restrict__ TL,
    float* __restrict__ out)
{
    int tid = threadIdx.x;
    float p = 0.f;
    for (int i = tid; i < ROWS; i += 256) p += __logf(S[i]) - TL[i];
#pragma unroll
    for (int m = 1; m < 64; m <<= 1) p += __shfl_xor(p, m, 64);
    __shared__ float red[4];
    if ((tid & 63) == 0) red[tid >> 6] = p;
    __syncthreads();
    if (tid == 0)
        out[0] = (red[0] + red[1] + red[2] + red[3]) / (float)ROWS;
}

extern "C" void kernel_launch(void* const* d_in, const int* in_sizes, int n_in,
                              void* d_out, int out_size, void* d_ws, size_t ws_size,
                              hipStream_t stream)
{
    (void)in_sizes; (void)n_in; (void)out_size;
    const int*   inputs  = (const int*)d_in[0];
    const int*   targets = (const int*)d_in[1];
    const float* Wih = (const float*)d_in[2];
    const float* bih = (const float*)d_in[3];
    const float* Whh = (const float*)d_in[4];
    const float* bhh = (const float*)d_in[5];
    const float* Wfc = (const float*)d_in[6];
    const float* bfc = (const float*)d_in[7];

    float* S  = (float*)d_ws;                           // 4096 f32
    float* TL = S + ROWS;                               // 4096 f32
    float* xp = TL + ROWS;                              // [T][B][H] fp32, 4 MB
    __hip_bfloat16* hs = (__hip_bfloat16*)(xp + (size_t)SEQT * BATCH * HID); // 2 MB (swizzled)
    __hip_bfloat16* Wfcb = hs + (size_t)ROWS * HID;     // 32000x256 bf16 swizzled, 16 MB
    int* prog = (int*)(Wfcb + (size_t)VOCAB * HID);     // producer progress flag

    const size_t need = (size_t)(2 * ROWS) * 4 + (size_t)ROWS * HID * 4
                      + (size_t)ROWS * HID * 2 + (size_t)VOCAB * HID * 2 + 256;
    const int use_bf16b = (ws_size >= need) ? 1 : 0;

    xproj_kernel<<<(SEQT * BATCH * HID) / 256, 256, 0, stream>>>(
        inputs, Wih, bih, bhh, Wfc, xp, S, Wfcb, prog, use_bf16b);

    bool fused_ok = false;
    if (use_bf16b) {
        void* ka[] = {(void*)&xp, (void*)&Whh, (void*)&hs, (void*)&Wfcb,
                      (void*)&bfc, (void*)&targets, (void*)&S, (void*)&TL, (void*)&prog};
        hipError_t e = hipLaunchCooperativeKernel((const void*)rnnfc_kernel,
                                                  dim3(256), dim3(512), ka, 0, stream);
        fused_ok = (e == hipSuccess);
    }
    if (!fused_ok) {
        rnn_kernel<<<1, 512, 0, stream>>>(xp, Whh, hs);
        if (use_bf16b)
            fc_kernel<true><<<8192, 256, 0, stream>>>(hs, (const void*)Wfcb, bfc, targets, S, TL);
        else
            fc_kernel<false><<<8192, 256, 0, stream>>>(hs, (const void*)Wfc, bfc, targets, S, TL);
    }
    loss_kernel<<<1, 256, 0, stream>>>(S, TL, (float*)d_out);
}

// Round 6
// 442.119 us; speedup vs baseline: 2.9439x; 2.9439x over previous
//
#include <hip/hip_runtime.h>
#include <hip/hip_bf16.h>
#include <stdint.h>

#define VOCAB 32000
#define HID   256
#define BATCH 16
#define SEQT  256
#define ROWS  (BATCH*SEQT)   // 4096

typedef __attribute__((ext_vector_type(8))) short bf16x8_t;
typedef __attribute__((ext_vector_type(4))) float f32x4_t;

__device__ __forceinline__ short f2bs(float x) {
    __hip_bfloat16 h = __float2bfloat16(x);
    return *reinterpret_cast<short*>(&h);
}
__device__ __forceinline__ bf16x8_t cvt8(float4 a, float4 b) {
    union { short s[8]; bf16x8_t v; } u;
    u.s[0] = f2bs(a.x); u.s[1] = f2bs(a.y); u.s[2] = f2bs(a.z); u.s[3] = f2bs(a.w);
    u.s[4] = f2bs(b.x); u.s[5] = f2bs(b.y); u.s[6] = f2bs(b.z); u.s[7] = f2bs(b.w);
    return u.v;
}
// workgroup barrier draining ONLY lgkmcnt; vmem stays in flight
__device__ __forceinline__ void barrier_lds() {
    asm volatile("s_waitcnt lgkmcnt(0)\n\ts_barrier" ::: "memory");
}
// tanh via exp2: tanh(x) = 1 - 2/(2^(2*log2(e)*x)+1); saturates naturally.
__device__ __forceinline__ float tanh_exp(float x) {
    float e = __builtin_amdgcn_exp2f(x * 2.885390081777927f);
    return fmaf(-2.f, __builtin_amdgcn_rcpf(e + 1.f), 1.f);
}
// pack two f32 -> one dword of 2 bf16 (RNE), lo = first operand
__device__ __forceinline__ uint32_t pk_bf16(float lo, float hi) {
    uint32_t r;
    asm("v_cvt_pk_bf16_f32 %0, %1, %2" : "=v"(r) : "v"(lo), "v"(hi));
    return r;
}
// async global->LDS, 16B per lane: LDS dest = wave-uniform base + lane*16,
// global src = per-lane pointer. Counts against vmcnt.
__device__ __forceinline__ void gload_lds16(const short* g, short* lds_base) {
    __builtin_amdgcn_global_load_lds(
        (const __attribute__((address_space(1))) void*)g,
        (__attribute__((address_space(3))) void*)lds_base, 16, 0, 0);
}

// ===========================================================================
// Swizzled fragment layout (shared by A=hs and B=Wfcb):
//   element (row, k) -> swz[ (row>>4)*4096 + (k>>5)*512 + ((k>>3)&3)*128
//                            + (row&15)*8 + (k&7) ]
// A fragment (one 16-row tile, one ki) is 1 KB contiguous, lane-linear ->
// stageable with ONE global_load_lds wave-instruction.
// ===========================================================================

// ---------------------------------------------------------------------------
// K1: xp[t][b][h] = Wih[inputs[b][t]][h]+bih[h]+bhh[h]; zeroes S.
// (Wfcb conversion moved into rnncvt_kernel blocks 1+ to overlap with rnn.)
// ---------------------------------------------------------------------------
__global__ __launch_bounds__(256) void xproj_kernel(
    const int* __restrict__ inputs,
    const float* __restrict__ Wih,
    const float* __restrict__ bih,
    const float* __restrict__ bhh,
    float* __restrict__ xp,
    float* __restrict__ S)
{
    int idx = blockIdx.x * 256 + threadIdx.x;  // (t*16+b)*256 + h
    int h  = idx & 255;
    int tb = idx >> 8;
    int b  = tb & 15;
    int t  = tb >> 4;
    int id = inputs[b * SEQT + t];
    xp[idx] = Wih[(size_t)id * HID + h] + bih[h] + bhh[h];
    if (idx < ROWS) S[idx] = 0.0f;
}

// ---------------------------------------------------------------------------
// RNN producer core: 512 threads, 8 waves (proven R1/R2 config, 183 us).
// Lane owns cols (n0, n0+1); x folded into MFMA C-in; h written direct from
// registers to the swizzled global layout (plain stores; kernel-boundary
// flush makes them visible to fc).
// ---------------------------------------------------------------------------
__device__ void rnn_core(const float* __restrict__ xp,
                         const float* __restrict__ Whh,
                         __hip_bfloat16* __restrict__ hs)
{
    __shared__ __align__(8) short hbuf[2][16][264];   // +8 pad
    const int tid = threadIdx.x;
    const int l = tid & 63, w = tid >> 6;
    const int lr = l & 15, lh = l >> 4;
    const int n0 = w * 32 + lr * 2;
    // swizzled global base for this lane's column pair
    short* hsg = (short*)hs + (n0 >> 5) * 512 + (((n0 >> 3) & 3) * 128) + (n0 & 7);

    bf16x8_t bfrag[2][8];
#pragma unroll
    for (int nt = 0; nt < 2; nt++)
#pragma unroll
        for (int ki = 0; ki < 8; ki++) {
            const float4* p = (const float4*)(Whh + (size_t)(n0 + nt) * HID + ki * 32 + lh * 8);
            bfrag[nt][ki] = cvt8(p[0], p[1]);
        }
    for (int i = tid; i < 16 * 264; i += 512) ((short*)hbuf[0])[i] = 0;
    __syncthreads();

    float2 xva[4], xvb[4];
#pragma unroll
    for (int r = 0; r < 4; r++)
        xva[r] = *(const float2*)(xp + (lh * 4 + r) * HID + n0);

    auto step = [&](int SRC, int DST, float2* xc, float2* xn, int t) {
        bf16x8_t afr[8];
#pragma unroll
        for (int ki = 0; ki < 8; ki++)
            afr[ki] = *(const bf16x8_t*)(&hbuf[SRC][lr][ki * 32 + lh * 8]);

        f32x4_t a0a = {xc[0].x, xc[1].x, xc[2].x, xc[3].x};
        f32x4_t a1a = {xc[0].y, xc[1].y, xc[2].y, xc[3].y};
        f32x4_t a0b = {0.f, 0.f, 0.f, 0.f};
        f32x4_t a1b = {0.f, 0.f, 0.f, 0.f};
#pragma unroll
        for (int ki = 0; ki < 4; ki++) {
            a0a = __builtin_amdgcn_mfma_f32_16x16x32_bf16(afr[ki],     bfrag[0][ki],     a0a, 0, 0, 0);
            a0b = __builtin_amdgcn_mfma_f32_16x16x32_bf16(afr[ki + 4], bfrag[0][ki + 4], a0b, 0, 0, 0);
            a1a = __builtin_amdgcn_mfma_f32_16x16x32_bf16(afr[ki],     bfrag[1][ki],     a1a, 0, 0, 0);
            a1b = __builtin_amdgcn_mfma_f32_16x16x32_bf16(afr[ki + 4], bfrag[1][ki + 4], a1b, 0, 0, 0);
        }

        if (t + 1 < SEQT) {
            const float* xb = xp + (size_t)(t + 1) * (BATCH * HID);
#pragma unroll
            for (int r = 0; r < 4; r++)
                xn[r] = *(const float2*)(xb + (lh * 4 + r) * HID + n0);
        }

#pragma unroll
        for (int r = 0; r < 4; r++) {
            float v0 = a0a[r] + a0b[r];
            float v1 = a1a[r] + a1b[r];
            uint32_t pk = pk_bf16(tanh_exp(v0), tanh_exp(v1));
            *(uint32_t*)(&hbuf[DST][lh * 4 + r][n0]) = pk;
            *(uint32_t*)(hsg + (size_t)t * 4096 + (lh * 4 + r) * 8) = pk;  // direct h store
        }
        barrier_lds();
    };

    for (int t = 0; t < SEQT; t += 2) {
        step(0, 1, xva, xvb, t);
        step(1, 0, xvb, xva, t + 1);
    }
}

// ---------------------------------------------------------------------------
// K2: block 0 = RNN recurrence (1 CU); blocks 1..256 = Wfcb fp32->bf16
// swizzled conversion (independent work riding on the 255 idle CUs).
// No intra-kernel consumption of either product -> no coherence hazard.
// ---------------------------------------------------------------------------
__global__ __launch_bounds__(512, 1) void rnncvt_kernel(
    const float* __restrict__ xp,
    const float* __restrict__ Whh,
    __hip_bfloat16* __restrict__ hs,
    const float* __restrict__ Wfc,
    __hip_bfloat16* __restrict__ Wfcb,
    int do_cvt)
{
    if (blockIdx.x == 0) { rnn_core(xp, Whh, hs); return; }
    if (!do_cvt) return;
    for (int idx = (int)(blockIdx.x - 1) * 512 + threadIdx.x;
         idx < (VOCAB * HID / 8); idx += 256 * 512) {
        // dst-linear: e = idx*8 shorts in swizzled Wfcb; decode -> (row,k)
        int e   = idx * 8;
        int m   = (e >> 3) & 15;
        int lhh = (e >> 7) & 3;
        int ki  = (e >> 9) & 7;
        int tile = e >> 12;
        const float4* p = (const float4*)(Wfc + (size_t)(tile * 16 + m) * HID
                                          + ki * 32 + lhh * 8);
        *(bf16x8_t*)((short*)Wfcb + (size_t)e) = cvt8(p[0], p[1]);
    }
}

// ---------------------------------------------------------------------------
// K3: fused FC GEMM + exp-rowsum + target-logit extraction (R4-proven).
// 8192 blocks, 128x128 tile, XCD swizzle (FETCH 16MB), global_load_lds
// staging + counted-vmcnt(4) 2-slab pipeline, lgkm-only barriers.
// ---------------------------------------------------------------------------
template <bool BF16B>
__global__ __launch_bounds__(256) void fc_kernel(
    const __hip_bfloat16* __restrict__ hsz,   // A swizzled
    const void* __restrict__ WfcP,            // BF16B: swizzled bf16; else raw fp32
    const float* __restrict__ bfc,
    const int* __restrict__ targets,
    float* __restrict__ S,
    float* __restrict__ TL)
{
    __shared__ __align__(16) short As[2][8 * 512];
    __shared__ __align__(16) short Bs[2][8 * 512];
    __shared__ int tgt[128];

    const int bid = blockIdx.x;
    const int xcd = bid & 7;
    const int j   = bid >> 3;
    const int m_id = j & 31;
    const int n_id = (j >> 5) * 8 + xcd;
    if (n_id >= VOCAB / 128) return;
    const int m0 = m_id * 128, n0 = n_id * 128;

    const int tid = threadIdx.x;
    const int l = tid & 63, w = tid >> 6;
    const int lr = l & 15, lh = l >> 4;
    const int wm = (w >> 1) * 64, wn = (w & 1) * 64;

    if (tid < 128) {
        int r = m0 + tid;                        // r = t*16+b
        tgt[tid] = targets[((r & 15) << 8) | (r >> 4)];
    }
    __builtin_amdgcn_sched_barrier(0);

    const short* Ag = (const short*)hsz + (size_t)m_id * 32768 + (size_t)(w * 2) * 4096 + l * 8;
    const short* Bg = (const short*)WfcP + (size_t)n_id * 32768 + (size_t)(w * 2) * 4096 + l * 8;
    const float* Bf = (const float*)WfcP;

    f32x4_t acc[4][4];
    const f32x4_t z = {0.f, 0.f, 0.f, 0.f};
#pragma unroll
    for (int i = 0; i < 4; i++)
#pragma unroll
        for (int jj = 0; jj < 4; jj++) acc[i][jj] = z;

    if (BF16B) {
        auto stage = [&](int buf, int s) {
            gload_lds16(Ag + s * 512,        &As[buf][(w * 2) * 512]);
            gload_lds16(Ag + 4096 + s * 512, &As[buf][(w * 2 + 1) * 512]);
            gload_lds16(Bg + s * 512,        &Bs[buf][(w * 2) * 512]);
            gload_lds16(Bg + 4096 + s * 512, &Bs[buf][(w * 2 + 1) * 512]);
        };
        stage(0, 0);
        stage(1, 1);
        __builtin_amdgcn_sched_barrier(0);

#pragma unroll
        for (int s = 0; s < 8; s++) {
            const int buf = s & 1;
            if (s < 7) asm volatile("s_waitcnt vmcnt(4)\n\ts_barrier" ::: "memory");
            else       asm volatile("s_waitcnt vmcnt(0)\n\ts_barrier" ::: "memory");

            bf16x8_t a[4], b[4];
#pragma unroll
            for (int mt = 0; mt < 4; mt++)
                a[mt] = *(const bf16x8_t*)&As[buf][(((w >> 1) * 4 + mt) * 512) + l * 8];
#pragma unroll
            for (int nt = 0; nt < 4; nt++)
                b[nt] = *(const bf16x8_t*)&Bs[buf][(((w & 1) * 4 + nt) * 512) + l * 8];

            if (s < 6) {
                barrier_lds();
                stage(buf, s + 2);
                __builtin_amdgcn_sched_barrier(0);
            }
#pragma unroll
            for (int mt = 0; mt < 4; mt++)
#pragma unroll
                for (int nt = 0; nt < 4; nt++)
                    acc[mt][nt] = __builtin_amdgcn_mfma_f32_16x16x32_bf16(
                        a[mt], b[nt], acc[mt][nt], 0, 0, 0);
        }
    } else {
        for (int s = 0; s < 8; s++) {
            __syncthreads();
#pragma unroll
            for (int i = 0; i < 2; i++) {
                int tt = w * 2 + i;
                bf16x8_t va = *(const bf16x8_t*)(Ag + i * 4096 + s * 512);
                *(bf16x8_t*)&As[0][tt * 512 + l * 8] = va;
                int n = n0 + tt * 16 + lr;
                const float4* p = (const float4*)(Bf + (size_t)n * HID + s * 32 + lh * 8);
                *(bf16x8_t*)&Bs[0][tt * 512 + l * 8] = cvt8(p[0], p[1]);
            }
            __syncthreads();
            bf16x8_t a[4], b[4];
#pragma unroll
            for (int mt = 0; mt < 4; mt++)
                a[mt] = *(const bf16x8_t*)&As[0][(((w >> 1) * 4 + mt) * 512) + l * 8];
#pragma unroll
            for (int nt = 0; nt < 4; nt++)
                b[nt] = *(const bf16x8_t*)&Bs[0][(((w & 1) * 4 + nt) * 512) + l * 8];
#pragma unroll
            for (int mt = 0; mt < 4; mt++)
#pragma unroll
                for (int nt = 0; nt < 4; nt++)
                    acc[mt][nt] = __builtin_amdgcn_mfma_f32_16x16x32_bf16(
                        a[mt], b[nt], acc[mt][nt], 0, 0, 0);
        }
    }

    int tg[16];
#pragma unroll
    for (int i = 0; i < 16; i++)
        tg[i] = tgt[wm + (i >> 2) * 16 + lh * 4 + (i & 3)];

    float rsum[16];
#pragma unroll
    for (int i = 0; i < 16; i++) rsum[i] = 0.f;
#pragma unroll
    for (int nt = 0; nt < 4; nt++) {
        int n = n0 + wn + nt * 16 + lr;
        float bias = bfc[n];
#pragma unroll
        for (int mt = 0; mt < 4; mt++)
#pragma unroll
            for (int r = 0; r < 4; r++) {
                float v = acc[mt][nt][r] + bias;
                rsum[mt * 4 + r] += __expf(v);
                if (tg[mt * 4 + r] == n)
                    TL[m0 + wm + mt * 16 + lh * 4 + r] = v;
            }
    }
#pragma unroll
    for (int m = 1; m < 16; m <<= 1)
#pragma unroll
        for (int i = 0; i < 16; i++) rsum[i] += __shfl_xor(rsum[i], m, 64);
    if (lr == 0) {
#pragma unroll
        for (int i = 0; i < 16; i++) {
            int r = m0 + wm + (i >> 2) * 16 + lh * 4 + (i & 3);
            atomicAdd(&S[r], rsum[i]);
        }
    }
}

// ---------------------------------------------------------------------------
// K4: loss = mean_r( log(S[r]) - TL[r] )
// ---------------------------------------------------------------------------
__global__ __launch_bounds__(256) void loss_kernel(
    const float* __restrict__ S,
    const float* __restrict__ TL,
    float* __restrict__ out)
{
    int tid = threadIdx.x;
    float p = 0.f;
    for (int i = tid; i < ROWS; i += 256) p += __logf(S[i]) - TL[i];
#pragma unroll
    for (int m = 1; m < 64; m <<= 1) p += __shfl_xor(p, m, 64);
    __shared__ float red[4];
    if ((tid & 63) == 0) red[tid >> 6] = p;
    __syncthreads();
    if (tid == 0)
        out[0] = (red[0] + red[1] + red[2] + red[3]) / (float)ROWS;
}

extern "C" void kernel_launch(void* const* d_in, const int* in_sizes, int n_in,
                              void* d_out, int out_size, void* d_ws, size_t ws_size,
                              hipStream_t stream)
{
    (void)in_sizes; (void)n_in; (void)out_size;
    const int*   inputs  = (const int*)d_in[0];
    const int*   targets = (const int*)d_in[1];
    const float* Wih = (const float*)d_in[2];
    const float* bih = (const float*)d_in[3];
    const float* Whh = (const float*)d_in[4];
    const float* bhh = (const float*)d_in[5];
    const float* Wfc = (const float*)d_in[6];
    const float* bfc = (const float*)d_in[7];

    float* S  = (float*)d_ws;                           // 4096 f32
    float* TL = S + ROWS;                               // 4096 f32
    float* xp = TL + ROWS;                              // [T][B][H] fp32, 4 MB
    __hip_bfloat16* hs = (__hip_bfloat16*)(xp + (size_t)SEQT * BATCH * HID); // 2 MB (swizzled)
    __hip_bfloat16* Wfcb = hs + (size_t)ROWS * HID;     // 32000x256 bf16 swizzled, 16 MB

    const size_t need = (size_t)(2 * ROWS) * 4 + (size_t)ROWS * HID * 4
                      + (size_t)ROWS * HID * 2 + (size_t)VOCAB * HID * 2;
    const int use_bf16b = (ws_size >= need) ? 1 : 0;

    xproj_kernel<<<(SEQT * BATCH * HID) / 256, 256, 0, stream>>>(
        inputs, Wih, bih, bhh, xp, S);
    rnncvt_kernel<<<257, 512, 0, stream>>>(xp, Whh, hs, Wfc, Wfcb, use_bf16b);
    if (use_bf16b)
        fc_kernel<true><<<8192, 256, 0, stream>>>(hs, (const void*)Wfcb, bfc, targets, S, TL);
    else
        fc_kernel<false><<<8192, 256, 0, stream>>>(hs, (const void*)Wfc, bfc, targets, S, TL);
    loss_kernel<<<1, 256, 0, stream>>>(S, TL, (float*)d_out);
}

// Round 7
// 440.405 us; speedup vs baseline: 2.9554x; 1.0039x over previous
//
#include <hip/hip_runtime.h>
#include <hip/hip_bf16.h>
#include <stdint.h>

#define VOCAB 32000
#define HID   256
#define BATCH 16
#define SEQT  256
#define ROWS  (BATCH*SEQT)   // 4096

typedef __attribute__((ext_vector_type(8))) short bf16x8_t;
typedef __attribute__((ext_vector_type(4))) float f32x4_t;

__device__ __forceinline__ short f2bs(float x) {
    __hip_bfloat16 h = __float2bfloat16(x);
    return *reinterpret_cast<short*>(&h);
}
__device__ __forceinline__ bf16x8_t cvt8(float4 a, float4 b) {
    union { short s[8]; bf16x8_t v; } u;
    u.s[0] = f2bs(a.x); u.s[1] = f2bs(a.y); u.s[2] = f2bs(a.z); u.s[3] = f2bs(a.w);
    u.s[4] = f2bs(b.x); u.s[5] = f2bs(b.y); u.s[6] = f2bs(b.z); u.s[7] = f2bs(b.w);
    return u.v;
}
// workgroup barrier draining ONLY lgkmcnt; vmem stays in flight
__device__ __forceinline__ void barrier_lds() {
    asm volatile("s_waitcnt lgkmcnt(0)\n\ts_barrier" ::: "memory");
}
// tanh via exp2: tanh(x) = 1 - 2/(2^(2*log2(e)*x)+1); saturates naturally.
__device__ __forceinline__ float tanh_exp(float x) {
    float e = __builtin_amdgcn_exp2f(x * 2.885390081777927f);
    return fmaf(-2.f, __builtin_amdgcn_rcpf(e + 1.f), 1.f);
}
// pack two f32 -> one dword of 2 bf16 (RNE), lo = first operand
__device__ __forceinline__ uint32_t pk_bf16(float lo, float hi) {
    uint32_t r;
    asm("v_cvt_pk_bf16_f32 %0, %1, %2" : "=v"(r) : "v"(lo), "v"(hi));
    return r;
}
// async global->LDS, 16B per lane: LDS dest = wave-uniform base + lane*16
__device__ __forceinline__ void gload_lds16(const short* g, short* lds_base) {
    __builtin_amdgcn_global_load_lds(
        (const __attribute__((address_space(1))) void*)g,
        (__attribute__((address_space(3))) void*)lds_base, 16, 0, 0);
}

// ===========================================================================
// Swizzled fragment layout (shared by A=hs and B=Wfcb):
//   element (row, k) -> swz[ (row>>4)*4096 + (k>>5)*512 + ((k>>3)&3)*128
//                            + (row&15)*8 + (k&7) ]
// A fragment (one 16-row tile, one ki) is 1 KB contiguous, lane-linear.
// ===========================================================================

// ---------------------------------------------------------------------------
// K1: xp[t][b][h] = Wih[inputs[b][t]][h]+bih[h]+bhh[h]; zeroes S.
// ---------------------------------------------------------------------------
__global__ __launch_bounds__(256) void xproj_kernel(
    const int* __restrict__ inputs,
    const float* __restrict__ Wih,
    const float* __restrict__ bih,
    const float* __restrict__ bhh,
    float* __restrict__ xp,
    float* __restrict__ S)
{
    int idx = blockIdx.x * 256 + threadIdx.x;  // (t*16+b)*256 + h
    int h  = idx & 255;
    int tb = idx >> 8;
    int b  = tb & 15;
    int t  = tb >> 4;
    int id = inputs[b * SEQT + t];
    xp[idx] = Wih[(size_t)id * HID + h] + bih[h] + bhh[h];
    if (idx < ROWS) S[idx] = 0.0f;
}

// ---------------------------------------------------------------------------
// RNN core: R2-EXACT structure (183 us proven). 512 threads, 8 waves; lane
// owns cols (n0, n0+1); x folded into MFMA C-in; h_{t-1} copied LDS->global
// as ONE coalesced bf16x8 store per thread per step (pipelined).
// ---------------------------------------------------------------------------
__device__ void rnn_core(const float* __restrict__ xp,
                         const float* __restrict__ Whh,
                         __hip_bfloat16* __restrict__ hs)
{
    __shared__ short hbuf[2][16][264];     // +8 pad
    const int tid = threadIdx.x;
    const int l = tid & 63, w = tid >> 6;
    const int lr = l & 15, lh = l >> 4;
    const int cm = tid >> 5;               // copy: row (=b) 0..15
    const int cc = (tid & 31) * 8;         // copy: col (x8 shorts)
    const int n0 = w * 32 + lr * 2;        // this lane's even column
    // swizzled dest offset within a 16-row tile (tile index = t)
    const int cpoff = ((cc >> 5) * 512) + (((cc >> 3) & 3) * 128) + cm * 8;

    bf16x8_t bfrag[2][8];
#pragma unroll
    for (int nt = 0; nt < 2; nt++)
#pragma unroll
        for (int ki = 0; ki < 8; ki++) {
            const float4* p = (const float4*)(Whh + (size_t)(n0 + nt) * HID + ki * 32 + lh * 8);
            bfrag[nt][ki] = cvt8(p[0], p[1]);
        }
    for (int i = tid; i < 16 * 264; i += 512) ((short*)hbuf[0])[i] = 0;
    __syncthreads();

    float2 xva[4], xvb[4];
#pragma unroll
    for (int r = 0; r < 4; r++)
        xva[r] = *(const float2*)(xp + (lh * 4 + r) * HID + n0);

    auto step = [&](int SRC, int DST, float2* xc, float2* xn, int t) {
        if (t > 0) {
            bf16x8_t hv = *(const bf16x8_t*)(&hbuf[SRC][cm][cc]);
            *(bf16x8_t*)((short*)hs + (size_t)(t - 1) * 4096 + cpoff) = hv;
        }
        bf16x8_t afr[8];
#pragma unroll
        for (int ki = 0; ki < 8; ki++)
            afr[ki] = *(const bf16x8_t*)(&hbuf[SRC][lr][ki * 32 + lh * 8]);

        f32x4_t a0a = {xc[0].x, xc[1].x, xc[2].x, xc[3].x};
        f32x4_t a1a = {xc[0].y, xc[1].y, xc[2].y, xc[3].y};
        f32x4_t a0b = {0.f, 0.f, 0.f, 0.f};
        f32x4_t a1b = {0.f, 0.f, 0.f, 0.f};
#pragma unroll
        for (int ki = 0; ki < 4; ki++) {
            a0a = __builtin_amdgcn_mfma_f32_16x16x32_bf16(afr[ki],     bfrag[0][ki],     a0a, 0, 0, 0);
            a0b = __builtin_amdgcn_mfma_f32_16x16x32_bf16(afr[ki + 4], bfrag[0][ki + 4], a0b, 0, 0, 0);
            a1a = __builtin_amdgcn_mfma_f32_16x16x32_bf16(afr[ki],     bfrag[1][ki],     a1a, 0, 0, 0);
            a1b = __builtin_amdgcn_mfma_f32_16x16x32_bf16(afr[ki + 4], bfrag[1][ki + 4], a1b, 0, 0, 0);
        }

        if (t + 1 < SEQT) {
            const float* xb = xp + (size_t)(t + 1) * (BATCH * HID);
#pragma unroll
            for (int r = 0; r < 4; r++)
                xn[r] = *(const float2*)(xb + (lh * 4 + r) * HID + n0);
        }

#pragma unroll
        for (int r = 0; r < 4; r++) {
            float v0 = a0a[r] + a0b[r];
            float v1 = a1a[r] + a1b[r];
            uint32_t pk = pk_bf16(tanh_exp(v0), tanh_exp(v1));
            *(uint32_t*)(&hbuf[DST][lh * 4 + r][n0]) = pk;
        }
        barrier_lds();
    };

    for (int t = 0; t < SEQT; t += 2) {
        step(0, 1, xva, xvb, t);
        step(1, 0, xvb, xva, t + 1);
    }
    bf16x8_t hv = *(const bf16x8_t*)(&hbuf[0][cm][cc]);
    *(bf16x8_t*)((short*)hs + (size_t)(SEQT - 1) * 4096 + cpoff) = hv;
}

// ---------------------------------------------------------------------------
// K2: block 0 = RNN; blocks 1..256 = Wfcb fp32->bf16 swizzled conversion
// (free ride on the idle CUs; no intra-kernel consumption -> no coherence).
// ---------------------------------------------------------------------------
__global__ __launch_bounds__(512, 1) void rnncvt_kernel(
    const float* __restrict__ xp,
    const float* __restrict__ Whh,
    __hip_bfloat16* __restrict__ hs,
    const float* __restrict__ Wfc,
    __hip_bfloat16* __restrict__ Wfcb,
    int do_cvt)
{
    if (blockIdx.x == 0) { rnn_core(xp, Whh, hs); return; }
    if (!do_cvt) return;
    for (int idx = (int)(blockIdx.x - 1) * 512 + threadIdx.x;
         idx < (VOCAB * HID / 8); idx += 256 * 512) {
        int e   = idx * 8;
        int m   = (e >> 3) & 15;
        int lhh = (e >> 7) & 3;
        int ki  = (e >> 9) & 7;
        int tile = e >> 12;
        const float4* p = (const float4*)(Wfc + (size_t)(tile * 16 + m) * HID
                                          + ki * 32 + lhh * 8);
        *(bf16x8_t*)((short*)Wfcb + (size_t)e) = cvt8(p[0], p[1]);
    }
}

// ---------------------------------------------------------------------------
// K3: STATIONARY-B FC. 250 blocks x 512 thr; block j owns cols [128j,128j+128)
// for the whole GEMM. Per wave: 32 B-fragments in REGISTERS (loaded once);
// A (hs, L2-hot) streamed through dbuf LDS in 64-row m-tiles, ONE
// global_load_lds stage + ONE barrier per m-tile (stage issued a full m-tile
// ~2500cy ahead -> latency hidden; K-loop touches only LDS+regs).
// Row-sums accumulate in LDS (ds_add), flushed to Sp[j][4096] (no atomics).
// ---------------------------------------------------------------------------
__global__ __launch_bounds__(512, 1) void fc_sb_kernel(
    const __hip_bfloat16* __restrict__ hsz,   // A swizzled
    const __hip_bfloat16* __restrict__ Wfcb,  // B swizzled
    const float* __restrict__ bfc,
    const int* __restrict__ targets,
    float* __restrict__ Sp,                   // [250][4096] partial rowsums
    float* __restrict__ TL)
{
    __shared__ __align__(16) short As[2 * 4 * 8 * 512];   // 64 KB
    __shared__ float rsum[ROWS];                          // 16 KB
    __shared__ int tgtb[2][64];

    const int j = blockIdx.x;                 // col-stripe
    const int tid = threadIdx.x;
    const int l = tid & 63, w = tid >> 6;     // 8 waves
    const int lr = l & 15, lh = l >> 4;
    const int wr = w >> 1;                    // row-tile 0..3 in m-tile
    const int wc = w & 1;                     // col half (64 cols)

    // B fragments -> registers: col-tiles j*8 + wc*4 + {0..3}
    bf16x8_t Br0[8], Br1[8], Br2[8], Br3[8];
    {
        const short* BW = (const short*)Wfcb + (size_t)(j * 8 + wc * 4) * 4096 + l * 8;
#pragma unroll
        for (int ki = 0; ki < 8; ki++) {
            Br0[ki] = *(const bf16x8_t*)(BW + 0 * 4096 + ki * 512);
            Br1[ki] = *(const bf16x8_t*)(BW + 1 * 4096 + ki * 512);
            Br2[ki] = *(const bf16x8_t*)(BW + 2 * 4096 + ki * 512);
            Br3[ki] = *(const bf16x8_t*)(BW + 3 * 4096 + ki * 512);
        }
    }
    const int colbase = j * 128 + wc * 64 + lr;
    const float bias0 = bfc[colbase];
    const float bias1 = bfc[colbase + 16];
    const float bias2 = bfc[colbase + 32];
    const float bias3 = bfc[colbase + 48];

    for (int i = tid; i < ROWS; i += 512) rsum[i] = 0.f;

    const short* AG = (const short*)hsz;
    auto stageA = [&](int buf, int m) {   // wave w stages its 4 fragments
        const short* src = AG + ((size_t)(m * 4 + wr) * 8 + wc * 4) * 512 + l * 8;
        short* dst = As + ((buf * 4 + wr) * 8 + wc * 4) * 512;
#pragma unroll
        for (int q = 0; q < 4; q++)
            gload_lds16(src + q * 512, dst + q * 512);
    };

    stageA(0, 0);
    if (tid < 64) tgtb[0][tid] = targets[((tid & 15) << 8) | (tid >> 4)];  // m=0 rows
    __syncthreads();

    for (int m = 0; m < 64; m++) {
        const int buf = m & 1;
        int tnext = 0;
        if (m < 63) {
            stageA(buf ^ 1, m + 1);
            if (tid < 64) {
                int row = (m + 1) * 64 + tid;
                tnext = targets[((row & 15) << 8) | (row >> 4)];
            }
        }

        f32x4_t acc0 = {0,0,0,0}, acc1 = {0,0,0,0}, acc2 = {0,0,0,0}, acc3 = {0,0,0,0};
        const short* Ab = As + ((buf * 4 + wr) * 8) * 512 + l * 8;
#pragma unroll
        for (int ki = 0; ki < 8; ki++) {
            bf16x8_t a = *(const bf16x8_t*)(Ab + ki * 512);
            acc0 = __builtin_amdgcn_mfma_f32_16x16x32_bf16(a, Br0[ki], acc0, 0, 0, 0);
            acc1 = __builtin_amdgcn_mfma_f32_16x16x32_bf16(a, Br1[ki], acc1, 0, 0, 0);
            acc2 = __builtin_amdgcn_mfma_f32_16x16x32_bf16(a, Br2[ki], acc2, 0, 0, 0);
            acc3 = __builtin_amdgcn_mfma_f32_16x16x32_bf16(a, Br3[ki], acc3, 0, 0, 0);
        }

        const int rowbase = m * 64 + wr * 16 + lh * 4;
        int4 tg = *(const int4*)&tgtb[buf][wr * 16 + lh * 4];
        float rs0 = 0.f, rs1 = 0.f, rs2 = 0.f, rs3 = 0.f;

#define FC_EPI(ACC, BIAS, OFF) {                                         \
        int col = colbase + OFF;                                         \
        float v0 = ACC[0] + BIAS, v1 = ACC[1] + BIAS;                    \
        float v2 = ACC[2] + BIAS, v3 = ACC[3] + BIAS;                    \
        rs0 += __expf(v0); rs1 += __expf(v1);                            \
        rs2 += __expf(v2); rs3 += __expf(v3);                            \
        if (tg.x == col) TL[rowbase + 0] = v0;                           \
        if (tg.y == col) TL[rowbase + 1] = v1;                           \
        if (tg.z == col) TL[rowbase + 2] = v2;                           \
        if (tg.w == col) TL[rowbase + 3] = v3; }

        FC_EPI(acc0, bias0, 0)
        FC_EPI(acc1, bias1, 16)
        FC_EPI(acc2, bias2, 32)
        FC_EPI(acc3, bias3, 48)
#undef FC_EPI

#pragma unroll
        for (int d = 1; d < 16; d <<= 1) {
            rs0 += __shfl_xor(rs0, d, 64);
            rs1 += __shfl_xor(rs1, d, 64);
            rs2 += __shfl_xor(rs2, d, 64);
            rs3 += __shfl_xor(rs3, d, 64);
        }
        if (lr == 0) {          // 2 waves (wc=0,1) add same rows -> ds_add
            atomicAdd(&rsum[rowbase + 0], rs0);
            atomicAdd(&rsum[rowbase + 1], rs1);
            atomicAdd(&rsum[rowbase + 2], rs2);
            atomicAdd(&rsum[rowbase + 3], rs3);
        }

        if (m < 63) {
            if (tid < 64) tgtb[buf ^ 1][tid] = tnext;
            __syncthreads();   // drains gload_lds (vmcnt) + ds ops; buf swap safe
        }
    }
    __syncthreads();
    // flush partial row-sums (coalesced, no atomics)
    float* SpRow = Sp + (size_t)j * ROWS;
    *(float4*)(SpRow + tid * 8)     = *(const float4*)(rsum + tid * 8);
    *(float4*)(SpRow + tid * 8 + 4) = *(const float4*)(rsum + tid * 8 + 4);
}

// ---------------------------------------------------------------------------
// loss stage 1: per row r, total = sum_j Sp[j][r]; val = log(total) - TL[r];
// block-reduce -> part[bid]. 16 blocks x 256.
// ---------------------------------------------------------------------------
__global__ __launch_bounds__(256) void loss1_kernel(
    const float* __restrict__ Sp,
    const float* __restrict__ TL,
    float* __restrict__ part)
{
    const int tid = threadIdx.x;
    const int r = blockIdx.x * 256 + tid;
    float tot = 0.f;
#pragma unroll 5
    for (int jj = 0; jj < 250; jj++) tot += Sp[(size_t)jj * ROWS + r];
    float val = __logf(tot) - TL[r];
#pragma unroll
    for (int d = 1; d < 64; d <<= 1) val += __shfl_xor(val, d, 64);
    __shared__ float red[4];
    if ((tid & 63) == 0) red[tid >> 6] = val;
    __syncthreads();
    if (tid == 0)
        part[blockIdx.x] = red[0] + red[1] + red[2] + red[3];
}
__global__ __launch_bounds__(64) void loss2_kernel(
    const float* __restrict__ part, float* __restrict__ out)
{
    int tid = threadIdx.x;
    float p = (tid < 16) ? part[tid] : 0.f;
#pragma unroll
    for (int d = 1; d < 64; d <<= 1) p += __shfl_xor(p, d, 64);
    if (tid == 0) out[0] = p / (float)ROWS;
}

// ---------------------------------------------------------------------------
// Fallback FC (tiny workspace): fp32 B, register staging, atomic S.
// ---------------------------------------------------------------------------
__global__ __launch_bounds__(256) void fc_fb_kernel(
    const __hip_bfloat16* __restrict__ hsz,
    const float* __restrict__ Bf,
    const float* __restrict__ bfc,
    const int* __restrict__ targets,
    float* __restrict__ S,
    float* __restrict__ TL)
{
    __shared__ __align__(16) short As[8 * 512];
    __shared__ __align__(16) short Bs[8 * 512];
    __shared__ int tgt[128];

    const int bid = blockIdx.x;
    const int xcd = bid & 7;
    const int j   = bid >> 3;
    const int m_id = j & 31;
    const int n_id = (j >> 5) * 8 + xcd;
    if (n_id >= VOCAB / 128) return;
    const int m0 = m_id * 128, n0 = n_id * 128;

    const int tid = threadIdx.x;
    const int l = tid & 63, w = tid >> 6;
    const int lr = l & 15, lh = l >> 4;
    const int wm = (w >> 1) * 64, wn = (w & 1) * 64;

    if (tid < 128) {
        int r = m0 + tid;
        tgt[tid] = targets[((r & 15) << 8) | (r >> 4)];
    }
    const short* Ag = (const short*)hsz + (size_t)m_id * 32768 + (size_t)(w * 2) * 4096 + l * 8;

    f32x4_t acc[4][4];
    const f32x4_t z = {0.f, 0.f, 0.f, 0.f};
#pragma unroll
    for (int i = 0; i < 4; i++)
#pragma unroll
        for (int jj = 0; jj < 4; jj++) acc[i][jj] = z;

    for (int s = 0; s < 8; s++) {
        __syncthreads();
#pragma unroll
        for (int i = 0; i < 2; i++) {
            int tt = w * 2 + i;
            bf16x8_t va = *(const bf16x8_t*)(Ag + i * 4096 + s * 512);
            *(bf16x8_t*)&As[tt * 512 + l * 8] = va;
            int n = n0 + tt * 16 + lr;
            const float4* p = (const float4*)(Bf + (size_t)n * HID + s * 32 + lh * 8);
            *(bf16x8_t*)&Bs[tt * 512 + l * 8] = cvt8(p[0], p[1]);
        }
        __syncthreads();
        bf16x8_t a[4], b[4];
#pragma unroll
        for (int mt = 0; mt < 4; mt++)
            a[mt] = *(const bf16x8_t*)&As[(((w >> 1) * 4 + mt) * 512) + l * 8];
#pragma unroll
        for (int nt = 0; nt < 4; nt++)
            b[nt] = *(const bf16x8_t*)&Bs[(((w & 1) * 4 + nt) * 512) + l * 8];
#pragma unroll
        for (int mt = 0; mt < 4; mt++)
#pragma unroll
            for (int nt = 0; nt < 4; nt++)
                acc[mt][nt] = __builtin_amdgcn_mfma_f32_16x16x32_bf16(
                    a[mt], b[nt], acc[mt][nt], 0, 0, 0);
    }

    int tg[16];
#pragma unroll
    for (int i = 0; i < 16; i++)
        tg[i] = tgt[wm + (i >> 2) * 16 + lh * 4 + (i & 3)];
    float rsum[16];
#pragma unroll
    for (int i = 0; i < 16; i++) rsum[i] = 0.f;
#pragma unroll
    for (int nt = 0; nt < 4; nt++) {
        int n = n0 + wn + nt * 16 + lr;
        float bias = bfc[n];
#pragma unroll
        for (int mt = 0; mt < 4; mt++)
#pragma unroll
            for (int r = 0; r < 4; r++) {
                float v = acc[mt][nt][r] + bias;
                rsum[mt * 4 + r] += __expf(v);
                if (tg[mt * 4 + r] == n)
                    TL[m0 + wm + mt * 16 + lh * 4 + r] = v;
            }
    }
#pragma unroll
    for (int m = 1; m < 16; m <<= 1)
#pragma unroll
        for (int i = 0; i < 16; i++) rsum[i] += __shfl_xor(rsum[i], m, 64);
    if (lr == 0) {
#pragma unroll
        for (int i = 0; i < 16; i++) {
            int r = m0 + wm + (i >> 2) * 16 + lh * 4 + (i & 3);
            atomicAdd(&S[r], rsum[i]);
        }
    }
}

__global__ __launch_bounds__(256) void loss_kernel(
    const float* __restrict__ S,
    const float* __restrict__ TL,
    float* __restrict__ out)
{
    int tid = threadIdx.x;
    float p = 0.f;
    for (int i = tid; i < ROWS; i += 256) p += __logf(S[i]) - TL[i];
#pragma unroll
    for (int m = 1; m < 64; m <<= 1) p += __shfl_xor(p, m, 64);
    __shared__ float red[4];
    if ((tid & 63) == 0) red[tid >> 6] = p;
    __syncthreads();
    if (tid == 0)
        out[0] = (red[0] + red[1] + red[2] + red[3]) / (float)ROWS;
}

extern "C" void kernel_launch(void* const* d_in, const int* in_sizes, int n_in,
                              void* d_out, int out_size, void* d_ws, size_t ws_size,
                              hipStream_t stream)
{
    (void)in_sizes; (void)n_in; (void)out_size;
    const int*   inputs  = (const int*)d_in[0];
    const int*   targets = (const int*)d_in[1];
    const float* Wih = (const float*)d_in[2];
    const float* bih = (const float*)d_in[3];
    const float* Whh = (const float*)d_in[4];
    const float* bhh = (const float*)d_in[5];
    const float* Wfc = (const float*)d_in[6];
    const float* bfc = (const float*)d_in[7];

    float* S  = (float*)d_ws;                           // 4096 f32 (+16 part)
    float* TL = S + ROWS;                               // 4096 f32
    float* xp = TL + ROWS;                              // [T][B][H] fp32, 4 MB
    float* Sp = xp;                                     // Sp[250][4096] ALIASES xp (dead after rnn)
    __hip_bfloat16* hs = (__hip_bfloat16*)(xp + (size_t)SEQT * BATCH * HID); // 2 MB swizzled
    __hip_bfloat16* Wfcb = hs + (size_t)ROWS * HID;     // 16 MB swizzled

    const size_t need = (size_t)(2 * ROWS) * 4 + (size_t)ROWS * HID * 4
                      + (size_t)ROWS * HID * 2 + (size_t)VOCAB * HID * 2;
    const int use_bf16b = (ws_size >= need) ? 1 : 0;

    xproj_kernel<<<(SEQT * BATCH * HID) / 256, 256, 0, stream>>>(
        inputs, Wih, bih, bhh, xp, S);
    rnncvt_kernel<<<257, 512, 0, stream>>>(xp, Whh, hs, Wfc, Wfcb, use_bf16b);
    if (use_bf16b) {
        fc_sb_kernel<<<250, 512, 0, stream>>>(hs, Wfcb, bfc, targets, Sp, TL);
        loss1_kernel<<<16, 256, 0, stream>>>(Sp, TL, S);
        loss2_kernel<<<1, 64, 0, stream>>>(S, (float*)d_out);
    } else {
        fc_fb_kernel<<<8192, 256, 0, stream>>>(hs, Wfc, bfc, targets, S, TL);
        loss_kernel<<<1, 256, 0, stream>>>(S, TL, (float*)d_out);
    }
}